// Round 7
// baseline (815.577 us; speedup 1.0000x reference)
//
#include <hip/hip_runtime.h>

// MHA fwd: B=4, T=2048, D=1024, H=16, DK=64. Inputs/outputs f32 (flag-detected), compute bf16 MFMA.
// d_in: 0=x, 1=mask(ignored), 2=wq, 3=bq, 4=wk, 5=bk, 6=wv, 7=bv, 8=wo, 9=bo

typedef short s16x8 __attribute__((ext_vector_type(8)));
typedef short s16x4 __attribute__((ext_vector_type(4)));
typedef float f32x4 __attribute__((ext_vector_type(4)));

static __device__ __forceinline__ float bf2f(unsigned short u) {
    return __uint_as_float(((unsigned int)u) << 16);
}
static __device__ __forceinline__ unsigned short f2bf(float f) {
    unsigned int x = __float_as_uint(f);
    unsigned int r = x + 0x7fffu + ((x >> 16) & 1u);  // RTNE
    return (unsigned short)(r >> 16);
}

static __device__ __forceinline__ void gload_lds16(const short* g, short* l) {
    __builtin_amdgcn_global_load_lds((__attribute__((address_space(1))) void*)g,
                                     (__attribute__((address_space(3))) void*)l, 16, 0, 0);
}

// DPP max-reduction over the 16-lane DPP row (valid tree: xor1, xor2, half_mirror, mirror)
#define DPP_MAX(v, ctrl)                                                                       \
    v = fmaxf(v, __int_as_float(__builtin_amdgcn_update_dpp(0, __float_as_int(v), ctrl, 0xF, 0xF, true)))
static __device__ __forceinline__ float rowmax16(float v) {
    DPP_MAX(v, 0xB1);   // quad_perm [1,0,3,2]  (xor 1)
    DPP_MAX(v, 0x4E);   // quad_perm [2,3,0,1]  (xor 2)
    DPP_MAX(v, 0x141);  // row_half_mirror
    DPP_MAX(v, 0x140);  // row_mirror
    return v;
}

// ---- dtype detection ----
__global__ __launch_bounds__(64) void detect_dtype(const unsigned short* __restrict__ x,
                                                   int* __restrict__ flag) {
    int lane = threadIdx.x;
    int cnt = 0;
    for (int i = 0; i < 64; ++i) {
        float v = bf2f(x[lane * 64 + i]);
        if (!(fabsf(v) < 1e10f)) cnt++;
    }
    unsigned long long m = __ballot(cnt > 0);
    if (lane == 0) *flag = (m != 0ull) ? 1 : 0;
}

// ---- generic convert ----
__global__ __launch_bounds__(256) void convert_bf16(const void* __restrict__ src,
                                                    unsigned short* __restrict__ dst,
                                                    int n, const int* __restrict__ flag) {
    int i = blockIdx.x * 256 + threadIdx.x;
    if (i >= n) return;
    if (*flag) dst[i] = f2bf(((const float*)src)[i]);
    else       dst[i] = ((const unsigned short*)src)[i];
}

// ---- 4 biases in one launch ----
__global__ __launch_bounds__(256) void convert_biases(const void* __restrict__ b0,
                                                      const void* __restrict__ b1,
                                                      const void* __restrict__ b2,
                                                      const void* __restrict__ b3,
                                                      unsigned short* __restrict__ dst,
                                                      const int* __restrict__ flag) {
    int i = blockIdx.x * 256 + threadIdx.x;
    const void* src = (i < 1024) ? b0 : (i < 2048 ? b1 : (i < 3072 ? b2 : b3));
    int k = i & 1023;
    if (*flag) dst[i] = f2bf(((const float*)src)[k]);
    else       dst[i] = ((const unsigned short*)src)[k];
}

// ---- weight transpose (+inline convert) ----
__global__ __launch_bounds__(256) void transpose_wt(const void* __restrict__ src,
                                                    unsigned short* __restrict__ dst,
                                                    const int* __restrict__ flag) {
    __shared__ unsigned short t[32][33];
    int f = *flag;
    int x = threadIdx.x, y = threadIdx.y;
    int n0 = blockIdx.x * 32, k0 = blockIdx.y * 32;
    for (int j = 0; j < 32; j += 8) {
        size_t idx = (size_t)(k0 + y + j) * 1024 + n0 + x;
        t[y + j][x] = f ? f2bf(((const float*)src)[idx]) : ((const unsigned short*)src)[idx];
    }
    __syncthreads();
    for (int j = 0; j < 32; j += 8) dst[(size_t)(n0 + y + j) * 1024 + k0 + x] = t[x][y + j];
}

// ---- GEMM: C = A.Bt + bias; V-columns (col>=2048, fuse_v) write straight to vt layout ----
__global__ __launch_bounds__(256) void gemm_bf16(const short* __restrict__ A,
                                                 const short* __restrict__ Bt,
                                                 void* __restrict__ C,
                                                 short* __restrict__ vt,
                                                 const unsigned short* __restrict__ bq,
                                                 const unsigned short* __restrict__ bk,
                                                 const unsigned short* __restrict__ bv,
                                                 int K, int ldc,
                                                 const int* __restrict__ flag, int f32out,
                                                 int scale_q, int fuse_v) {
    __shared__ __align__(16) short As[128][32];
    __shared__ __align__(16) short Bs[128][32];
    int tid = threadIdx.x;
    int wid = tid >> 6, lane = tid & 63, quad = lane >> 4, l16 = lane & 15;
    int wm = wid & 1, wn = wid >> 1;
    int m0 = blockIdx.x * 128, n0 = blockIdx.y * 128;
    bool wf = f32out && (*flag != 0);

    int lrow = lane >> 2;
    int lcol = (lane & 3) * 8;
    const short* Ag0 = A  + (size_t)(m0 + wid * 32 + lrow) * K + lcol;
    const short* Ag1 = A  + (size_t)(m0 + wid * 32 + 16 + lrow) * K + lcol;
    const short* Bg0 = Bt + (size_t)(n0 + wid * 32 + lrow) * K + lcol;
    const short* Bg1 = Bt + (size_t)(n0 + wid * 32 + 16 + lrow) * K + lcol;
    short* Al0 = &As[wid * 32][0];
    short* Al1 = &As[wid * 32 + 16][0];
    short* Bl0 = &Bs[wid * 32][0];
    short* Bl1 = &Bs[wid * 32 + 16][0];

    f32x4 acc[4][4] = {};
    for (int k0 = 0; k0 < K; k0 += 32) {
        __syncthreads();
        gload_lds16(Ag0 + k0, Al0);
        gload_lds16(Ag1 + k0, Al1);
        gload_lds16(Bg0 + k0, Bl0);
        gload_lds16(Bg1 + k0, Bl1);
        __syncthreads();
        s16x8 a[4], b[4];
        for (int i = 0; i < 4; ++i) a[i] = *(const s16x8*)&As[wm * 64 + i * 16 + l16][quad * 8];
        for (int j = 0; j < 4; ++j) b[j] = *(const s16x8*)&Bs[wn * 64 + j * 16 + l16][quad * 8];
        for (int i = 0; i < 4; ++i)
            for (int j = 0; j < 4; ++j)
                acc[i][j] = __builtin_amdgcn_mfma_f32_16x16x32_bf16(a[i], b[j], acc[i][j], 0, 0, 0);
    }
    for (int j = 0; j < 4; ++j) {
        int col = n0 + wn * 64 + j * 16 + l16;
        const unsigned short* bptr = (col < 1024) ? bq : (col < 2048 ? bk : bv);
        float bias = bf2f(bptr[col & 1023]);
        float cs = (scale_q && col < 1024) ? 0.18033688f : 1.0f;   // 1/sqrt(64) * log2(e)
        for (int i = 0; i < 4; ++i) {
            int rbase = m0 + wm * 64 + i * 16 + quad * 4;          // global row; same b for r=0..3
            if (fuse_v && col >= 2048) {
                int h = (col - 2048) >> 6, dk = col & 63;
                int bb_ = rbase >> 11, t = rbase & 2047;
                s16x4 pk;
                for (int r = 0; r < 4; ++r) pk[r] = (short)f2bf(acc[i][j][r] + bias);
                *(s16x4*)(vt + ((size_t)((bb_ * 16 + h) * 64 + dk)) * 2048 + t) = pk;
            } else {
                for (int r = 0; r < 4; ++r) {
                    float v = (acc[i][j][r] + bias) * cs;
                    size_t idx = (size_t)(rbase + r) * ldc + col;
                    if (wf) ((float*)C)[idx] = v;
                    else    ((unsigned short*)C)[idx] = f2bf(v);
                }
            }
        }
    }
}

// ---- flash attention fragments ----
struct KF { s16x8 lo[4], hi[4]; };
struct VF { s16x8 lo[4], hi[4]; };

static __device__ __forceinline__ void load_k(KF& f, const short* kbase, int kt, int l16, int quad) {
    const short* kp = kbase + (size_t)kt * 64 * 3072;
    for (int j = 0; j < 4; ++j) {
        const short* kr = kp + (size_t)(j * 16 + l16) * 3072;
        f.lo[j] = *(const s16x8*)(kr + quad * 8);
        f.hi[j] = *(const s16x8*)(kr + 32 + quad * 8);
    }
}
static __device__ __forceinline__ void load_v(VF& f, const short* vbase, int kt, int l16, int quad) {
    const short* vp = vbase + kt * 64;
    for (int d = 0; d < 4; ++d) {
        const short* vr = vp + (size_t)(d * 16 + l16) * 2048;
        f.lo[d] = *(const s16x8*)(vr + quad * 8);
        f.hi[d] = *(const s16x8*)(vr + 32 + quad * 8);
    }
}

static __device__ __forceinline__ void softmax_frag(f32x4* s, bool diag, int rbase, int l16, int quad,
                                                    short* PsW, float* m_old, f32x4& lacc, f32x4* o) {
    float mn[4];
    bool grew = false;
    for (int r = 0; r < 4; ++r) {
        if (diag) {
            int rowi = rbase + r;
            for (int j = 0; j < 4; ++j)
                if (j * 16 + l16 > rowi) s[j][r] = -INFINITY;
        }
        float mx = fmaxf(fmaxf(s[0][r], s[1][r]), fmaxf(s[2][r], s[3][r]));
        mx = rowmax16(mx);
        grew |= (mx > m_old[r]);
        mn[r] = fmaxf(m_old[r], mx);
    }
    if (__any(grew)) {        // wave-uniform: rescale only when the running max moved
        for (int r = 0; r < 4; ++r) {
            float alpha = exp2f(m_old[r] - mn[r]);
            m_old[r] = mn[r];
            lacc[r] *= alpha;
            for (int d = 0; d < 4; ++d) o[d][r] *= alpha;
        }
    }
    for (int r = 0; r < 4; ++r)
        for (int j = 0; j < 4; ++j) {
            float p = exp2f(s[j][r] - m_old[r]);
            unsigned int u = __float_as_uint(p) + 0x8000u;   // round-half-up bf16
            PsW[(quad * 4 + r) * 68 + j * 16 + l16] = (short)(u >> 16);
        }
}

static __device__ __forceinline__ void pv_frag(const short* PsW, const VF& V, const s16x8& ones,
                                               int l16, int quad, f32x4& lacc, f32x4* o) {
    // same-wave LDS RAW: DS ops are program-ordered per wave
    s16x8 pa0 = *(const s16x8*)&PsW[l16 * 68 + quad * 8];
    s16x8 pa1 = *(const s16x8*)&PsW[l16 * 68 + 32 + quad * 8];
    lacc = __builtin_amdgcn_mfma_f32_16x16x32_bf16(pa0, ones, lacc, 0, 0, 0);
    lacc = __builtin_amdgcn_mfma_f32_16x16x32_bf16(pa1, ones, lacc, 0, 0, 0);
    for (int d = 0; d < 4; ++d) {
        o[d] = __builtin_amdgcn_mfma_f32_16x16x32_bf16(pa0, V.lo[d], o[d], 0, 0, 0);
        o[d] = __builtin_amdgcn_mfma_f32_16x16x32_bf16(pa1, V.hi[d], o[d], 0, 0, 0);
    }
}

static __device__ __forceinline__ void tile_body(
    const KF& K, const VF& V, int kt, int kmax0, int kmax1,
    const s16x8& q00, const s16x8& q01, const s16x8& q10, const s16x8& q11,
    const s16x8& ones, short* Ps0, short* Ps1, int l16, int quad, int rbase,
    float* m0, f32x4& l0, f32x4* o0, float* m1, f32x4& l1, f32x4* o1) {
    bool act0 = kt <= kmax0;
    f32x4 s0[4] = {}, s1[4] = {};
    if (act0)
        for (int j = 0; j < 4; ++j) {
            s0[j] = __builtin_amdgcn_mfma_f32_16x16x32_bf16(q00, K.lo[j], s0[j], 0, 0, 0);
            s0[j] = __builtin_amdgcn_mfma_f32_16x16x32_bf16(q01, K.hi[j], s0[j], 0, 0, 0);
        }
    for (int j = 0; j < 4; ++j) {
        s1[j] = __builtin_amdgcn_mfma_f32_16x16x32_bf16(q10, K.lo[j], s1[j], 0, 0, 0);
        s1[j] = __builtin_amdgcn_mfma_f32_16x16x32_bf16(q11, K.hi[j], s1[j], 0, 0, 0);
    }
    if (act0) softmax_frag(s0, kt == kmax0, rbase, l16, quad, Ps0, m0, l0, o0);
    softmax_frag(s1, kt == kmax1, rbase, l16, quad, Ps1, m1, l1, o1);
    if (act0) pv_frag(Ps0, V, ones, l16, quad, l0, o0);
    pv_frag(Ps1, V, ones, l16, quad, l1, o1);
}

// grid (64, 16): x = bh (XCD swizzle: id%8 = bh%8 -> one head per XCD L2), y -> qb = 15-y
// (big q-blocks dispatch first). One 128-row q-block per block; 4 waves x two 16-row frags.
// 1024 blocks = 4/CU; __launch_bounds__(256,4) caps VGPR at 128 (current usage) for 16 waves/CU.
__global__ __launch_bounds__(256, 4) void attn(const short* __restrict__ qkv,
                                               const short* __restrict__ vt,
                                               unsigned short* __restrict__ y) {
    __shared__ __align__(16) short Ps[2][4][16][68];
    int tid = threadIdx.x;
    int wid = tid >> 6, lane = tid & 63, quad = lane >> 4, l16 = lane & 15;
    int bh = blockIdx.x, b = bh >> 4, h = bh & 15;
    int qb = 15 - (int)blockIdx.y;
    int kmax0 = 2 * qb, kmax1 = 2 * qb + 1;
    const short* kbase = qkv + (size_t)b * 2048 * 3072 + 1024 + h * 64;
    const short* vbase = vt + (size_t)bh * 64 * 2048;
    short* Ps0 = &Ps[0][wid][0][0];
    short* Ps1 = &Ps[1][wid][0][0];
    int rbase = wid * 16 + quad * 4;

    s16x8 ones;
    for (int e = 0; e < 8; ++e) ones[e] = (short)0x3F80;   // bf16 1.0

    const short* qp0 = qkv + (size_t)(b * 2048 + qb * 128 + wid * 16 + l16) * 3072 + h * 64;
    const short* qp1 = qp0 + (size_t)64 * 3072;
    s16x8 q00 = *(const s16x8*)(qp0 + quad * 8);
    s16x8 q01 = *(const s16x8*)(qp0 + 32 + quad * 8);
    s16x8 q10 = *(const s16x8*)(qp1 + quad * 8);
    s16x8 q11 = *(const s16x8*)(qp1 + 32 + quad * 8);

    float m0[4], m1[4];
    for (int r = 0; r < 4; ++r) { m0[r] = -INFINITY; m1[r] = -INFINITY; }
    f32x4 l0 = {0.f, 0.f, 0.f, 0.f}, l1 = {0.f, 0.f, 0.f, 0.f};
    f32x4 o0[4] = {}, o1[4] = {};

    KF KA, KB;
    VF V;
    load_k(KA, kbase, 0, l16, quad);
    int kt = 0;
    for (;;) {
        if (kt < kmax1) load_k(KB, kbase, kt + 1, l16, quad);   // prefetch t+1
        load_v(V, vbase, kt, l16, quad);
        tile_body(KA, V, kt, kmax0, kmax1, q00, q01, q10, q11, ones,
                  Ps0, Ps1, l16, quad, rbase, m0, l0, o0, m1, l1, o1);
        if (++kt > kmax1) break;
        if (kt < kmax1) load_k(KA, kbase, kt + 1, l16, quad);
        load_v(V, vbase, kt, l16, quad);
        tile_body(KB, V, kt, kmax0, kmax1, q00, q01, q10, q11, ones,
                  Ps0, Ps1, l16, quad, rbase, m0, l0, o0, m1, l1, o1);
        if (++kt > kmax1) break;
    }

    for (int r = 0; r < 4; ++r) {
        float inv = 1.f / l0[r];
        int t = qb * 128 + rbase + r;
        for (int d = 0; d < 4; ++d)
            y[(size_t)(b * 2048 + t) * 1024 + h * 64 + d * 16 + l16] = f2bf(o0[d][r] * inv);
    }
    for (int r = 0; r < 4; ++r) {
        float inv = 1.f / l1[r];
        int t = qb * 128 + 64 + rbase + r;
        for (int d = 0; d < 4; ++d)
            y[(size_t)(b * 2048 + t) * 1024 + h * 64 + d * 16 + l16] = f2bf(o1[d][r] * inv);
    }
}

extern "C" void kernel_launch(void* const* d_in, const int* in_sizes, int n_in,
                              void* d_out, int out_size, void* d_ws, size_t ws_size,
                              hipStream_t stream) {
    (void)in_sizes; (void)n_in; (void)out_size; (void)ws_size;
    const void* x  = d_in[0];
    const void* wq = d_in[2]; const void* bq = d_in[3];
    const void* wk = d_in[4]; const void* bk = d_in[5];
    const void* wv = d_in[6]; const void* bv = d_in[7];
    const void* wo = d_in[8]; const void* bo = d_in[9];

    const size_t MB = 1024 * 1024;
    char* ws = (char*)d_ws;
    unsigned short* wT  = (unsigned short*)ws;                 // 4x[1024][1024] bf16  [0,8MB)
    short* qkv = (short*)(ws + 8 * MB);                        // [8192][3072] bf16    [8,56)
    short* vt  = (short*)(ws + 56 * MB);                       // [64][64][2048] bf16  [56,72)
    unsigned short* xb = (unsigned short*)(ws + 72 * MB);      // x as bf16 (aliases yb)
    unsigned short* yb = (unsigned short*)(ws + 72 * MB);      // attn out (after xb dead)
    unsigned short* bb = (unsigned short*)(ws + 88 * MB);      // 4x1024 bf16 biases
    int* flag = (int*)(ws + 88 * MB + 64 * 1024);

    detect_dtype<<<1, 64, 0, stream>>>((const unsigned short*)x, flag);
    convert_bf16<<<32768, 256, 0, stream>>>(x, xb, 8388608, flag);
    convert_biases<<<16, 256, 0, stream>>>(bq, bk, bv, bo, bb, flag);

    dim3 tb(32, 8);
    transpose_wt<<<dim3(32, 32), tb, 0, stream>>>(wq, wT,                flag);
    transpose_wt<<<dim3(32, 32), tb, 0, stream>>>(wk, wT + 1024 * 1024,  flag);
    transpose_wt<<<dim3(32, 32), tb, 0, stream>>>(wv, wT + 2048 * 1024,  flag);
    transpose_wt<<<dim3(32, 32), tb, 0, stream>>>(wo, wT + 3072 * 1024,  flag);

    gemm_bf16<<<dim3(64, 24), 256, 0, stream>>>((const short*)xb, (const short*)wT,
                                                qkv, vt, bb, bb + 1024, bb + 2048,
                                                1024, 3072, flag, 0, 1, 1);
    attn<<<dim3(64, 16), 256, 0, stream>>>(qkv, vt, yb);
    gemm_bf16<<<dim3(64, 8), 256, 0, stream>>>((const short*)yb, (const short*)(wT + 3072 * 1024),
                                               d_out, nullptr, bb + 3072, bb + 3072, bb + 3072,
                                               1024, 1024, flag, 1, 0, 0);
}

// Round 8
// 381.282 us; speedup vs baseline: 2.1390x; 2.1390x over previous
//
#include <hip/hip_runtime.h>

// MHA fwd: B=4, T=2048, D=1024, H=16, DK=64. Inputs/outputs f32 (flag-detected), compute bf16 MFMA.
// d_in: 0=x, 1=mask(ignored), 2=wq, 3=bq, 4=wk, 5=bk, 6=wv, 7=bv, 8=wo, 9=bo

typedef short s16x8 __attribute__((ext_vector_type(8)));
typedef short s16x4 __attribute__((ext_vector_type(4)));
typedef float f32x4 __attribute__((ext_vector_type(4)));

static __device__ __forceinline__ float bf2f(unsigned short u) {
    return __uint_as_float(((unsigned int)u) << 16);
}
static __device__ __forceinline__ unsigned short f2bf(float f) {
    unsigned int x = __float_as_uint(f);
    unsigned int r = x + 0x7fffu + ((x >> 16) & 1u);  // RTNE
    return (unsigned short)(r >> 16);
}

static __device__ __forceinline__ void gload_lds16(const short* g, short* l) {
    __builtin_amdgcn_global_load_lds((__attribute__((address_space(1))) void*)g,
                                     (__attribute__((address_space(3))) void*)l, 16, 0, 0);
}

// DPP max-reduction over the 16-lane DPP row (valid tree: xor1, xor2, half_mirror, mirror)
#define DPP_MAX(v, ctrl)                                                                       \
    v = fmaxf(v, __int_as_float(__builtin_amdgcn_update_dpp(0, __float_as_int(v), ctrl, 0xF, 0xF, true)))
static __device__ __forceinline__ float rowmax16(float v) {
    DPP_MAX(v, 0xB1);   // quad_perm [1,0,3,2]  (xor 1)
    DPP_MAX(v, 0x4E);   // quad_perm [2,3,0,1]  (xor 2)
    DPP_MAX(v, 0x141);  // row_half_mirror
    DPP_MAX(v, 0x140);  // row_mirror
    return v;
}

// ---- dtype detection ----
__global__ __launch_bounds__(64) void detect_dtype(const unsigned short* __restrict__ x,
                                                   int* __restrict__ flag) {
    int lane = threadIdx.x;
    int cnt = 0;
    for (int i = 0; i < 64; ++i) {
        float v = bf2f(x[lane * 64 + i]);
        if (!(fabsf(v) < 1e10f)) cnt++;
    }
    unsigned long long m = __ballot(cnt > 0);
    if (lane == 0) *flag = (m != 0ull) ? 1 : 0;
}

// ---- generic convert ----
__global__ __launch_bounds__(256) void convert_bf16(const void* __restrict__ src,
                                                    unsigned short* __restrict__ dst,
                                                    int n, const int* __restrict__ flag) {
    int i = blockIdx.x * 256 + threadIdx.x;
    if (i >= n) return;
    if (*flag) dst[i] = f2bf(((const float*)src)[i]);
    else       dst[i] = ((const unsigned short*)src)[i];
}

// ---- 4 biases in one launch ----
__global__ __launch_bounds__(256) void convert_biases(const void* __restrict__ b0,
                                                      const void* __restrict__ b1,
                                                      const void* __restrict__ b2,
                                                      const void* __restrict__ b3,
                                                      unsigned short* __restrict__ dst,
                                                      const int* __restrict__ flag) {
    int i = blockIdx.x * 256 + threadIdx.x;
    const void* src = (i < 1024) ? b0 : (i < 2048 ? b1 : (i < 3072 ? b2 : b3));
    int k = i & 1023;
    if (*flag) dst[i] = f2bf(((const float*)src)[k]);
    else       dst[i] = ((const unsigned short*)src)[k];
}

// ---- weight transpose (+inline convert) ----
__global__ __launch_bounds__(256) void transpose_wt(const void* __restrict__ src,
                                                    unsigned short* __restrict__ dst,
                                                    const int* __restrict__ flag) {
    __shared__ unsigned short t[32][33];
    int f = *flag;
    int x = threadIdx.x, y = threadIdx.y;
    int n0 = blockIdx.x * 32, k0 = blockIdx.y * 32;
    for (int j = 0; j < 32; j += 8) {
        size_t idx = (size_t)(k0 + y + j) * 1024 + n0 + x;
        t[y + j][x] = f ? f2bf(((const float*)src)[idx]) : ((const unsigned short*)src)[idx];
    }
    __syncthreads();
    for (int j = 0; j < 32; j += 8) dst[(size_t)(n0 + y + j) * 1024 + k0 + x] = t[x][y + j];
}

// ---- GEMM: C = A.Bt + bias; V-columns (col>=2048, fuse_v) write straight to vt layout ----
__global__ __launch_bounds__(256) void gemm_bf16(const short* __restrict__ A,
                                                 const short* __restrict__ Bt,
                                                 void* __restrict__ C,
                                                 short* __restrict__ vt,
                                                 const unsigned short* __restrict__ bq,
                                                 const unsigned short* __restrict__ bk,
                                                 const unsigned short* __restrict__ bv,
                                                 int K, int ldc,
                                                 const int* __restrict__ flag, int f32out,
                                                 int scale_q, int fuse_v) {
    __shared__ __align__(16) short As[128][32];
    __shared__ __align__(16) short Bs[128][32];
    int tid = threadIdx.x;
    int wid = tid >> 6, lane = tid & 63, quad = lane >> 4, l16 = lane & 15;
    int wm = wid & 1, wn = wid >> 1;
    int m0 = blockIdx.x * 128, n0 = blockIdx.y * 128;
    bool wf = f32out && (*flag != 0);

    int lrow = lane >> 2;
    int lcol = (lane & 3) * 8;
    const short* Ag0 = A  + (size_t)(m0 + wid * 32 + lrow) * K + lcol;
    const short* Ag1 = A  + (size_t)(m0 + wid * 32 + 16 + lrow) * K + lcol;
    const short* Bg0 = Bt + (size_t)(n0 + wid * 32 + lrow) * K + lcol;
    const short* Bg1 = Bt + (size_t)(n0 + wid * 32 + 16 + lrow) * K + lcol;
    short* Al0 = &As[wid * 32][0];
    short* Al1 = &As[wid * 32 + 16][0];
    short* Bl0 = &Bs[wid * 32][0];
    short* Bl1 = &Bs[wid * 32 + 16][0];

    f32x4 acc[4][4] = {};
    for (int k0 = 0; k0 < K; k0 += 32) {
        __syncthreads();
        gload_lds16(Ag0 + k0, Al0);
        gload_lds16(Ag1 + k0, Al1);
        gload_lds16(Bg0 + k0, Bl0);
        gload_lds16(Bg1 + k0, Bl1);
        __syncthreads();
        s16x8 a[4], b[4];
        for (int i = 0; i < 4; ++i) a[i] = *(const s16x8*)&As[wm * 64 + i * 16 + l16][quad * 8];
        for (int j = 0; j < 4; ++j) b[j] = *(const s16x8*)&Bs[wn * 64 + j * 16 + l16][quad * 8];
        for (int i = 0; i < 4; ++i)
            for (int j = 0; j < 4; ++j)
                acc[i][j] = __builtin_amdgcn_mfma_f32_16x16x32_bf16(a[i], b[j], acc[i][j], 0, 0, 0);
    }
    for (int j = 0; j < 4; ++j) {
        int col = n0 + wn * 64 + j * 16 + l16;
        const unsigned short* bptr = (col < 1024) ? bq : (col < 2048 ? bk : bv);
        float bias = bf2f(bptr[col & 1023]);
        float cs = (scale_q && col < 1024) ? 0.18033688f : 1.0f;   // 1/sqrt(64) * log2(e)
        for (int i = 0; i < 4; ++i) {
            int rbase = m0 + wm * 64 + i * 16 + quad * 4;          // global row; same b for r=0..3
            if (fuse_v && col >= 2048) {
                int h = (col - 2048) >> 6, dk = col & 63;
                int bb_ = rbase >> 11, t = rbase & 2047;
                s16x4 pk;
                for (int r = 0; r < 4; ++r) pk[r] = (short)f2bf(acc[i][j][r] + bias);
                *(s16x4*)(vt + ((size_t)((bb_ * 16 + h) * 64 + dk)) * 2048 + t) = pk;
            } else {
                for (int r = 0; r < 4; ++r) {
                    float v = (acc[i][j][r] + bias) * cs;
                    size_t idx = (size_t)(rbase + r) * ldc + col;
                    if (wf) ((float*)C)[idx] = v;
                    else    ((unsigned short*)C)[idx] = f2bf(v);
                }
            }
        }
    }
}

// ---- flash attention fragments ----
struct KF { s16x8 lo[4], hi[4]; };
struct VF { s16x8 lo[4], hi[4]; };

static __device__ __forceinline__ void load_k(KF& f, const short* kbase, int kt, int l16, int quad) {
    const short* kp = kbase + (size_t)kt * 64 * 3072;
    for (int j = 0; j < 4; ++j) {
        const short* kr = kp + (size_t)(j * 16 + l16) * 3072;
        f.lo[j] = *(const s16x8*)(kr + quad * 8);
        f.hi[j] = *(const s16x8*)(kr + 32 + quad * 8);
    }
}
static __device__ __forceinline__ void load_v(VF& f, const short* vbase, int kt, int l16, int quad) {
    const short* vp = vbase + kt * 64;
    for (int d = 0; d < 4; ++d) {
        const short* vr = vp + (size_t)(d * 16 + l16) * 2048;
        f.lo[d] = *(const s16x8*)(vr + quad * 8);
        f.hi[d] = *(const s16x8*)(vr + 32 + quad * 8);
    }
}

static __device__ __forceinline__ void softmax_frag(f32x4* s, bool diag, int rbase, int l16, int quad,
                                                    short* PsW, float* m_old, f32x4& lacc, f32x4* o) {
    float mn[4];
    bool grew = false;
    for (int r = 0; r < 4; ++r) {
        if (diag) {
            int rowi = rbase + r;
            for (int j = 0; j < 4; ++j)
                if (j * 16 + l16 > rowi) s[j][r] = -INFINITY;
        }
        float mx = fmaxf(fmaxf(s[0][r], s[1][r]), fmaxf(s[2][r], s[3][r]));
        mx = rowmax16(mx);
        grew |= (mx > m_old[r]);
        mn[r] = fmaxf(m_old[r], mx);
    }
    if (__any(grew)) {        // wave-uniform: rescale only when the running max moved
        for (int r = 0; r < 4; ++r) {
            float alpha = exp2f(m_old[r] - mn[r]);
            m_old[r] = mn[r];
            lacc[r] *= alpha;
            for (int d = 0; d < 4; ++d) o[d][r] *= alpha;
        }
    }
    for (int r = 0; r < 4; ++r)
        for (int j = 0; j < 4; ++j) {
            float p = exp2f(s[j][r] - m_old[r]);
            unsigned int u = __float_as_uint(p) + 0x8000u;   // round-half-up bf16
            PsW[(quad * 4 + r) * 68 + j * 16 + l16] = (short)(u >> 16);
        }
}

static __device__ __forceinline__ void pv_frag(const short* PsW, const VF& V, const s16x8& ones,
                                               int l16, int quad, f32x4& lacc, f32x4* o) {
    // same-wave LDS RAW: DS ops are program-ordered per wave
    s16x8 pa0 = *(const s16x8*)&PsW[l16 * 68 + quad * 8];
    s16x8 pa1 = *(const s16x8*)&PsW[l16 * 68 + 32 + quad * 8];
    lacc = __builtin_amdgcn_mfma_f32_16x16x32_bf16(pa0, ones, lacc, 0, 0, 0);
    lacc = __builtin_amdgcn_mfma_f32_16x16x32_bf16(pa1, ones, lacc, 0, 0, 0);
    for (int d = 0; d < 4; ++d) {
        o[d] = __builtin_amdgcn_mfma_f32_16x16x32_bf16(pa0, V.lo[d], o[d], 0, 0, 0);
        o[d] = __builtin_amdgcn_mfma_f32_16x16x32_bf16(pa1, V.hi[d], o[d], 0, 0, 0);
    }
}

static __device__ __forceinline__ void tile_body(
    const KF& K, const VF& V, int kt, int kmax0, int kmax1,
    const s16x8& q00, const s16x8& q01, const s16x8& q10, const s16x8& q11,
    const s16x8& ones, short* Ps0, short* Ps1, int l16, int quad, int rbase,
    float* m0, f32x4& l0, f32x4* o0, float* m1, f32x4& l1, f32x4* o1) {
    bool act0 = kt <= kmax0;
    f32x4 s0[4] = {}, s1[4] = {};
    if (act0)
        for (int j = 0; j < 4; ++j) {
            s0[j] = __builtin_amdgcn_mfma_f32_16x16x32_bf16(q00, K.lo[j], s0[j], 0, 0, 0);
            s0[j] = __builtin_amdgcn_mfma_f32_16x16x32_bf16(q01, K.hi[j], s0[j], 0, 0, 0);
        }
    for (int j = 0; j < 4; ++j) {
        s1[j] = __builtin_amdgcn_mfma_f32_16x16x32_bf16(q10, K.lo[j], s1[j], 0, 0, 0);
        s1[j] = __builtin_amdgcn_mfma_f32_16x16x32_bf16(q11, K.hi[j], s1[j], 0, 0, 0);
    }
    if (act0) softmax_frag(s0, kt == kmax0, rbase, l16, quad, Ps0, m0, l0, o0);
    softmax_frag(s1, kt == kmax1, rbase, l16, quad, Ps1, m1, l1, o1);
    if (act0) pv_frag(Ps0, V, ones, l16, quad, l0, o0);
    pv_frag(Ps1, V, ones, l16, quad, l1, o1);
}

// grid (64, 16): x = bh (XCD swizzle: id%8 = bh%8 -> one head per XCD L2), y -> qb = 15-y
// (big q-blocks dispatch first). One 128-row q-block per block; 4 waves x two 16-row frags.
// 1024 blocks = 4/CU. NOTE: launch_bounds min-waves must stay 2 — requesting 4 waves/EU
// squeezed VGPR to 64 and spilled every fragment to scratch (R7: 2 GB HBM traffic, 4x slower).
// 128 VGPR already hardware-permits 4 waves/SIMD; the grid provides the TLP.
__global__ __launch_bounds__(256, 2) void attn(const short* __restrict__ qkv,
                                               const short* __restrict__ vt,
                                               unsigned short* __restrict__ y) {
    __shared__ __align__(16) short Ps[2][4][16][68];
    int tid = threadIdx.x;
    int wid = tid >> 6, lane = tid & 63, quad = lane >> 4, l16 = lane & 15;
    int bh = blockIdx.x, b = bh >> 4, h = bh & 15;
    int qb = 15 - (int)blockIdx.y;
    int kmax0 = 2 * qb, kmax1 = 2 * qb + 1;
    const short* kbase = qkv + (size_t)b * 2048 * 3072 + 1024 + h * 64;
    const short* vbase = vt + (size_t)bh * 64 * 2048;
    short* Ps0 = &Ps[0][wid][0][0];
    short* Ps1 = &Ps[1][wid][0][0];
    int rbase = wid * 16 + quad * 4;

    s16x8 ones;
    for (int e = 0; e < 8; ++e) ones[e] = (short)0x3F80;   // bf16 1.0

    const short* qp0 = qkv + (size_t)(b * 2048 + qb * 128 + wid * 16 + l16) * 3072 + h * 64;
    const short* qp1 = qp0 + (size_t)64 * 3072;
    s16x8 q00 = *(const s16x8*)(qp0 + quad * 8);
    s16x8 q01 = *(const s16x8*)(qp0 + 32 + quad * 8);
    s16x8 q10 = *(const s16x8*)(qp1 + quad * 8);
    s16x8 q11 = *(const s16x8*)(qp1 + 32 + quad * 8);

    float m0[4], m1[4];
    for (int r = 0; r < 4; ++r) { m0[r] = -INFINITY; m1[r] = -INFINITY; }
    f32x4 l0 = {0.f, 0.f, 0.f, 0.f}, l1 = {0.f, 0.f, 0.f, 0.f};
    f32x4 o0[4] = {}, o1[4] = {};

    KF KA, KB;
    VF V;
    load_k(KA, kbase, 0, l16, quad);
    int kt = 0;
    for (;;) {
        if (kt < kmax1) load_k(KB, kbase, kt + 1, l16, quad);   // prefetch t+1
        load_v(V, vbase, kt, l16, quad);
        tile_body(KA, V, kt, kmax0, kmax1, q00, q01, q10, q11, ones,
                  Ps0, Ps1, l16, quad, rbase, m0, l0, o0, m1, l1, o1);
        if (++kt > kmax1) break;
        if (kt < kmax1) load_k(KA, kbase, kt + 1, l16, quad);
        load_v(V, vbase, kt, l16, quad);
        tile_body(KB, V, kt, kmax0, kmax1, q00, q01, q10, q11, ones,
                  Ps0, Ps1, l16, quad, rbase, m0, l0, o0, m1, l1, o1);
        if (++kt > kmax1) break;
    }

    for (int r = 0; r < 4; ++r) {
        float inv = 1.f / l0[r];
        int t = qb * 128 + rbase + r;
        for (int d = 0; d < 4; ++d)
            y[(size_t)(b * 2048 + t) * 1024 + h * 64 + d * 16 + l16] = f2bf(o0[d][r] * inv);
    }
    for (int r = 0; r < 4; ++r) {
        float inv = 1.f / l1[r];
        int t = qb * 128 + 64 + rbase + r;
        for (int d = 0; d < 4; ++d)
            y[(size_t)(b * 2048 + t) * 1024 + h * 64 + d * 16 + l16] = f2bf(o1[d][r] * inv);
    }
}

extern "C" void kernel_launch(void* const* d_in, const int* in_sizes, int n_in,
                              void* d_out, int out_size, void* d_ws, size_t ws_size,
                              hipStream_t stream) {
    (void)in_sizes; (void)n_in; (void)out_size; (void)ws_size;
    const void* x  = d_in[0];
    const void* wq = d_in[2]; const void* bq = d_in[3];
    const void* wk = d_in[4]; const void* bk = d_in[5];
    const void* wv = d_in[6]; const void* bv = d_in[7];
    const void* wo = d_in[8]; const void* bo = d_in[9];

    const size_t MB = 1024 * 1024;
    char* ws = (char*)d_ws;
    unsigned short* wT  = (unsigned short*)ws;                 // 4x[1024][1024] bf16  [0,8MB)
    short* qkv = (short*)(ws + 8 * MB);                        // [8192][3072] bf16    [8,56)
    short* vt  = (short*)(ws + 56 * MB);                       // [64][64][2048] bf16  [56,72)
    unsigned short* xb = (unsigned short*)(ws + 72 * MB);      // x as bf16 (aliases yb)
    unsigned short* yb = (unsigned short*)(ws + 72 * MB);      // attn out (after xb dead)
    unsigned short* bb = (unsigned short*)(ws + 88 * MB);      // 4x1024 bf16 biases
    int* flag = (int*)(ws + 88 * MB + 64 * 1024);

    detect_dtype<<<1, 64, 0, stream>>>((const unsigned short*)x, flag);
    convert_bf16<<<32768, 256, 0, stream>>>(x, xb, 8388608, flag);
    convert_biases<<<16, 256, 0, stream>>>(bq, bk, bv, bo, bb, flag);

    dim3 tb(32, 8);
    transpose_wt<<<dim3(32, 32), tb, 0, stream>>>(wq, wT,                flag);
    transpose_wt<<<dim3(32, 32), tb, 0, stream>>>(wk, wT + 1024 * 1024,  flag);
    transpose_wt<<<dim3(32, 32), tb, 0, stream>>>(wv, wT + 2048 * 1024,  flag);
    transpose_wt<<<dim3(32, 32), tb, 0, stream>>>(wo, wT + 3072 * 1024,  flag);

    gemm_bf16<<<dim3(64, 24), 256, 0, stream>>>((const short*)xb, (const short*)wT,
                                                qkv, vt, bb, bb + 1024, bb + 2048,
                                                1024, 3072, flag, 0, 1, 1);
    attn<<<dim3(64, 16), 256, 0, stream>>>(qkv, vt, yb);
    gemm_bf16<<<dim3(64, 8), 256, 0, stream>>>((const short*)yb, (const short*)(wT + 3072 * 1024),
                                               d_out, nullptr, bb + 3072, bb + 3072, bb + 3072,
                                               1024, 1024, flag, 1, 0, 0);
}

// Round 9
// 348.818 us; speedup vs baseline: 2.3381x; 1.0931x over previous
//
#include <hip/hip_runtime.h>

// MHA fwd: B=4, T=2048, D=1024, H=16, DK=64. Inputs/outputs f32 (flag-detected), compute bf16 MFMA.
// d_in: 0=x, 1=mask(ignored), 2=wq, 3=bq, 4=wk, 5=bk, 6=wv, 7=bv, 8=wo, 9=bo

typedef short s16x8 __attribute__((ext_vector_type(8)));
typedef short s16x4 __attribute__((ext_vector_type(4)));
typedef float f32x4 __attribute__((ext_vector_type(4)));

static __device__ __forceinline__ float bf2f(unsigned short u) {
    return __uint_as_float(((unsigned int)u) << 16);
}
static __device__ __forceinline__ unsigned short f2bf(float f) {
    unsigned int x = __float_as_uint(f);
    unsigned int r = x + 0x7fffu + ((x >> 16) & 1u);  // RTNE
    return (unsigned short)(r >> 16);
}

static __device__ __forceinline__ void gload_lds16(const short* g, short* l) {
    __builtin_amdgcn_global_load_lds((__attribute__((address_space(1))) void*)g,
                                     (__attribute__((address_space(3))) void*)l, 16, 0, 0);
}

// DPP max-reduction over the 16-lane DPP row (valid tree: xor1, xor2, half_mirror, mirror)
#define DPP_MAX(v, ctrl)                                                                       \
    v = fmaxf(v, __int_as_float(__builtin_amdgcn_update_dpp(0, __float_as_int(v), ctrl, 0xF, 0xF, true)))
static __device__ __forceinline__ float rowmax16(float v) {
    DPP_MAX(v, 0xB1);   // quad_perm [1,0,3,2]  (xor 1)
    DPP_MAX(v, 0x4E);   // quad_perm [2,3,0,1]  (xor 2)
    DPP_MAX(v, 0x141);  // row_half_mirror
    DPP_MAX(v, 0x140);  // row_mirror
    return v;
}

// ---- dtype detection ----
__global__ __launch_bounds__(64) void detect_dtype(const unsigned short* __restrict__ x,
                                                   int* __restrict__ flag) {
    int lane = threadIdx.x;
    int cnt = 0;
    for (int i = 0; i < 64; ++i) {
        float v = bf2f(x[lane * 64 + i]);
        if (!(fabsf(v) < 1e10f)) cnt++;
    }
    unsigned long long m = __ballot(cnt > 0);
    if (lane == 0) *flag = (m != 0ull) ? 1 : 0;
}

// ---- generic convert ----
__global__ __launch_bounds__(256) void convert_bf16(const void* __restrict__ src,
                                                    unsigned short* __restrict__ dst,
                                                    int n, const int* __restrict__ flag) {
    int i = blockIdx.x * 256 + threadIdx.x;
    if (i >= n) return;
    if (*flag) dst[i] = f2bf(((const float*)src)[i]);
    else       dst[i] = ((const unsigned short*)src)[i];
}

// ---- 4 biases in one launch ----
__global__ __launch_bounds__(256) void convert_biases(const void* __restrict__ b0,
                                                      const void* __restrict__ b1,
                                                      const void* __restrict__ b2,
                                                      const void* __restrict__ b3,
                                                      unsigned short* __restrict__ dst,
                                                      const int* __restrict__ flag) {
    int i = blockIdx.x * 256 + threadIdx.x;
    const void* src = (i < 1024) ? b0 : (i < 2048 ? b1 : (i < 3072 ? b2 : b3));
    int k = i & 1023;
    if (*flag) dst[i] = f2bf(((const float*)src)[k]);
    else       dst[i] = ((const unsigned short*)src)[k];
}

// ---- weight transpose (+inline convert) ----
__global__ __launch_bounds__(256) void transpose_wt(const void* __restrict__ src,
                                                    unsigned short* __restrict__ dst,
                                                    const int* __restrict__ flag) {
    __shared__ unsigned short t[32][33];
    int f = *flag;
    int x = threadIdx.x, y = threadIdx.y;
    int n0 = blockIdx.x * 32, k0 = blockIdx.y * 32;
    for (int j = 0; j < 32; j += 8) {
        size_t idx = (size_t)(k0 + y + j) * 1024 + n0 + x;
        t[y + j][x] = f ? f2bf(((const float*)src)[idx]) : ((const unsigned short*)src)[idx];
    }
    __syncthreads();
    for (int j = 0; j < 32; j += 8) dst[(size_t)(n0 + y + j) * 1024 + k0 + x] = t[x][y + j];
}

// ---- GEMM: C = A.Bt + bias; V-columns (col>=2048, fuse_v) write straight to vt layout ----
__global__ __launch_bounds__(256) void gemm_bf16(const short* __restrict__ A,
                                                 const short* __restrict__ Bt,
                                                 void* __restrict__ C,
                                                 short* __restrict__ vt,
                                                 const unsigned short* __restrict__ bq,
                                                 const unsigned short* __restrict__ bk,
                                                 const unsigned short* __restrict__ bv,
                                                 int K, int ldc,
                                                 const int* __restrict__ flag, int f32out,
                                                 int scale_q, int fuse_v) {
    __shared__ __align__(16) short As[128][32];
    __shared__ __align__(16) short Bs[128][32];
    int tid = threadIdx.x;
    int wid = tid >> 6, lane = tid & 63, quad = lane >> 4, l16 = lane & 15;
    int wm = wid & 1, wn = wid >> 1;
    int m0 = blockIdx.x * 128, n0 = blockIdx.y * 128;
    bool wf = f32out && (*flag != 0);

    int lrow = lane >> 2;
    int lcol = (lane & 3) * 8;
    const short* Ag0 = A  + (size_t)(m0 + wid * 32 + lrow) * K + lcol;
    const short* Ag1 = A  + (size_t)(m0 + wid * 32 + 16 + lrow) * K + lcol;
    const short* Bg0 = Bt + (size_t)(n0 + wid * 32 + lrow) * K + lcol;
    const short* Bg1 = Bt + (size_t)(n0 + wid * 32 + 16 + lrow) * K + lcol;
    short* Al0 = &As[wid * 32][0];
    short* Al1 = &As[wid * 32 + 16][0];
    short* Bl0 = &Bs[wid * 32][0];
    short* Bl1 = &Bs[wid * 32 + 16][0];

    f32x4 acc[4][4] = {};
    for (int k0 = 0; k0 < K; k0 += 32) {
        __syncthreads();
        gload_lds16(Ag0 + k0, Al0);
        gload_lds16(Ag1 + k0, Al1);
        gload_lds16(Bg0 + k0, Bl0);
        gload_lds16(Bg1 + k0, Bl1);
        __syncthreads();
        s16x8 a[4], b[4];
        for (int i = 0; i < 4; ++i) a[i] = *(const s16x8*)&As[wm * 64 + i * 16 + l16][quad * 8];
        for (int j = 0; j < 4; ++j) b[j] = *(const s16x8*)&Bs[wn * 64 + j * 16 + l16][quad * 8];
        for (int i = 0; i < 4; ++i)
            for (int j = 0; j < 4; ++j)
                acc[i][j] = __builtin_amdgcn_mfma_f32_16x16x32_bf16(a[i], b[j], acc[i][j], 0, 0, 0);
    }
    for (int j = 0; j < 4; ++j) {
        int col = n0 + wn * 64 + j * 16 + l16;
        const unsigned short* bptr = (col < 1024) ? bq : (col < 2048 ? bk : bv);
        float bias = bf2f(bptr[col & 1023]);
        float cs = (scale_q && col < 1024) ? 0.18033688f : 1.0f;   // 1/sqrt(64) * log2(e)
        for (int i = 0; i < 4; ++i) {
            int rbase = m0 + wm * 64 + i * 16 + quad * 4;          // global row; same b for r=0..3
            if (fuse_v && col >= 2048) {
                int h = (col - 2048) >> 6, dk = col & 63;
                int bb_ = rbase >> 11, t = rbase & 2047;
                s16x4 pk;
                for (int r = 0; r < 4; ++r) pk[r] = (short)f2bf(acc[i][j][r] + bias);
                *(s16x4*)(vt + ((size_t)((bb_ * 16 + h) * 64 + dk)) * 2048 + t) = pk;
            } else {
                for (int r = 0; r < 4; ++r) {
                    float v = (acc[i][j][r] + bias) * cs;
                    size_t idx = (size_t)(rbase + r) * ldc + col;
                    if (wf) ((float*)C)[idx] = v;
                    else    ((unsigned short*)C)[idx] = f2bf(v);
                }
            }
        }
    }
}

// ---- flash attention with LDS-staged K/V (shared across 8 waves) ----
// LDS tile layout: 64 rows x 8 chunks(16B); chunk slot = global_chunk ^ (row&7)  (XOR swizzle:
// global_load_lds forbids padding; swizzle keeps ds_read_b128 fragment reads conflict-free).
static __device__ __forceinline__ void stage_tiles(const short* kbase, const short* vbase,
                                                   int kt, short* Kb, short* Vb,
                                                   int wid, int lane) {
    int row = wid * 8 + (lane >> 3);            // 0..63
    int c_src = (lane & 7) ^ (lane >> 3);       // source chunk for this slot
    const short* kg = kbase + (size_t)(kt * 64 + row) * 3072 + c_src * 8;
    const short* vg = vbase + (size_t)row * 2048 + kt * 64 + c_src * 8;
    gload_lds16(kg, Kb + wid * 512);            // wave-uniform LDS base + lane*16
    gload_lds16(vg, Vb + wid * 512);
}

static __device__ __forceinline__ s16x8 lds_frag(const short* buf, int row, int cg) {
    int slot = cg ^ (row & 7);
    return *(const s16x8*)(buf + row * 64 + slot * 8);
}

// grid (64, 8): x = bh (XCD swizzle: id%8 = bh%8), y -> q-block pair {y, 15-y} (uniform 36 iters).
// 512 threads = 8 waves; each wave owns 16 q-rows of the 128-row q-block.
// K/V double-buffered in LDS; one barrier per K-tile; staging overlaps compute.
// (512,4): 128-reg budget — per-wave state is now small (no K/V fragments), fits without spill.
__global__ __launch_bounds__(512, 4) void attn(const short* __restrict__ qkv,
                                               const short* __restrict__ vt,
                                               unsigned short* __restrict__ y) {
    __shared__ __align__(16) short Kbuf[2][64 * 64];
    __shared__ __align__(16) short Vbuf[2][64 * 64];
    __shared__ __align__(16) short Ps[8][16 * 68];
    int tid = threadIdx.x;
    int wid = tid >> 6, lane = tid & 63, quad = lane >> 4, l16 = lane & 15;
    int bh = blockIdx.x, b = bh >> 4, h = bh & 15;
    const short* kbase = qkv + (size_t)b * 2048 * 3072 + 1024 + h * 64;
    const short* vbase = vt + (size_t)bh * 64 * 2048;
    short* PsW = &Ps[wid][0];
    int rloc = (wid & 3) * 16 + quad * 4;       // row within the wave's 64-aligned half

    s16x8 ones;
    for (int e = 0; e < 8; ++e) ones[e] = (short)0x3F80;   // bf16 1.0

    for (int pass = 0; pass < 2; ++pass) {
        int qb = pass ? 15 - (int)blockIdx.y : (int)blockIdx.y;
        int ktmax = 2 * qb + 1;                 // always odd (pass-boundary buffer safety)
        int kmax_w = 2 * qb + (wid >> 2);       // causal limit for this wave's rows

        const short* qp = qkv + (size_t)(b * 2048 + qb * 128 + wid * 16 + l16) * 3072 + h * 64;
        s16x8 q0 = *(const s16x8*)(qp + quad * 8);
        s16x8 q1 = *(const s16x8*)(qp + 32 + quad * 8);

        float m_old[4];
        for (int r = 0; r < 4; ++r) m_old[r] = -INFINITY;
        f32x4 lacc = {0.f, 0.f, 0.f, 0.f};
        f32x4 o[4] = {};

        stage_tiles(kbase, vbase, 0, Kbuf[0], Vbuf[0], wid, lane);
        for (int kt = 0; kt <= ktmax; ++kt) {
            __syncthreads();    // drains vmcnt: buf[kt&1] staged; prior reads of other buf done
            if (kt < ktmax)
                stage_tiles(kbase, vbase, kt + 1, Kbuf[(kt + 1) & 1], Vbuf[(kt + 1) & 1], wid, lane);
            if (kt > kmax_w) continue;          // predicated compute; barriers stay uniform
            const short* Kb = Kbuf[kt & 1];
            const short* Vb = Vbuf[kt & 1];

            f32x4 s[4] = {};
            for (int j = 0; j < 4; ++j) {
                s16x8 klo = lds_frag(Kb, j * 16 + l16, quad);
                s16x8 khi = lds_frag(Kb, j * 16 + l16, 4 + quad);
                s[j] = __builtin_amdgcn_mfma_f32_16x16x32_bf16(q0, klo, s[j], 0, 0, 0);
                s[j] = __builtin_amdgcn_mfma_f32_16x16x32_bf16(q1, khi, s[j], 0, 0, 0);
            }

            bool diag = (kt == kmax_w);
            float mn[4];
            bool grew = false;
            for (int r = 0; r < 4; ++r) {
                if (diag) {
                    int rowi = rloc + r;
                    for (int j = 0; j < 4; ++j)
                        if (j * 16 + l16 > rowi) s[j][r] = -INFINITY;
                }
                float mx = fmaxf(fmaxf(s[0][r], s[1][r]), fmaxf(s[2][r], s[3][r]));
                mx = rowmax16(mx);
                grew |= (mx > m_old[r]);
                mn[r] = fmaxf(m_old[r], mx);
            }
            if (__any(grew)) {
                for (int r = 0; r < 4; ++r) {
                    float alpha = exp2f(m_old[r] - mn[r]);
                    m_old[r] = mn[r];
                    lacc[r] *= alpha;
                    for (int d = 0; d < 4; ++d) o[d][r] *= alpha;
                }
            }
            for (int r = 0; r < 4; ++r)
                for (int j = 0; j < 4; ++j) {
                    float p = exp2f(s[j][r] - m_old[r]);
                    unsigned int u = __float_as_uint(p) + 0x8000u;   // round-half-up bf16
                    PsW[(quad * 4 + r) * 68 + j * 16 + l16] = (short)(u >> 16);
                }

            // same-wave LDS RAW: DS ops program-ordered per wave
            s16x8 pa0 = *(const s16x8*)&PsW[l16 * 68 + quad * 8];
            s16x8 pa1 = *(const s16x8*)&PsW[l16 * 68 + 32 + quad * 8];
            lacc = __builtin_amdgcn_mfma_f32_16x16x32_bf16(pa0, ones, lacc, 0, 0, 0);
            lacc = __builtin_amdgcn_mfma_f32_16x16x32_bf16(pa1, ones, lacc, 0, 0, 0);
            for (int d = 0; d < 4; ++d) {
                s16x8 vlo = lds_frag(Vb, d * 16 + l16, quad);
                s16x8 vhi = lds_frag(Vb, d * 16 + l16, 4 + quad);
                o[d] = __builtin_amdgcn_mfma_f32_16x16x32_bf16(pa0, vlo, o[d], 0, 0, 0);
                o[d] = __builtin_amdgcn_mfma_f32_16x16x32_bf16(pa1, vhi, o[d], 0, 0, 0);
            }
        }

        for (int r = 0; r < 4; ++r) {
            float inv = 1.f / lacc[r];
            int t = qb * 128 + wid * 16 + quad * 4 + r;
            for (int d = 0; d < 4; ++d)
                y[(size_t)(b * 2048 + t) * 1024 + h * 64 + d * 16 + l16] = f2bf(o[d][r] * inv);
        }
    }
}

extern "C" void kernel_launch(void* const* d_in, const int* in_sizes, int n_in,
                              void* d_out, int out_size, void* d_ws, size_t ws_size,
                              hipStream_t stream) {
    (void)in_sizes; (void)n_in; (void)out_size; (void)ws_size;
    const void* x  = d_in[0];
    const void* wq = d_in[2]; const void* bq = d_in[3];
    const void* wk = d_in[4]; const void* bk = d_in[5];
    const void* wv = d_in[6]; const void* bv = d_in[7];
    const void* wo = d_in[8]; const void* bo = d_in[9];

    const size_t MB = 1024 * 1024;
    char* ws = (char*)d_ws;
    unsigned short* wT  = (unsigned short*)ws;                 // 4x[1024][1024] bf16  [0,8MB)
    short* qkv = (short*)(ws + 8 * MB);                        // [8192][3072] bf16    [8,56)
    short* vt  = (short*)(ws + 56 * MB);                       // [64][64][2048] bf16  [56,72)
    unsigned short* xb = (unsigned short*)(ws + 72 * MB);      // x as bf16 (aliases yb)
    unsigned short* yb = (unsigned short*)(ws + 72 * MB);      // attn out (after xb dead)
    unsigned short* bb = (unsigned short*)(ws + 88 * MB);      // 4x1024 bf16 biases
    int* flag = (int*)(ws + 88 * MB + 64 * 1024);

    detect_dtype<<<1, 64, 0, stream>>>((const unsigned short*)x, flag);
    convert_bf16<<<32768, 256, 0, stream>>>(x, xb, 8388608, flag);
    convert_biases<<<16, 256, 0, stream>>>(bq, bk, bv, bo, bb, flag);

    dim3 tb(32, 8);
    transpose_wt<<<dim3(32, 32), tb, 0, stream>>>(wq, wT,                flag);
    transpose_wt<<<dim3(32, 32), tb, 0, stream>>>(wk, wT + 1024 * 1024,  flag);
    transpose_wt<<<dim3(32, 32), tb, 0, stream>>>(wv, wT + 2048 * 1024,  flag);
    transpose_wt<<<dim3(32, 32), tb, 0, stream>>>(wo, wT + 3072 * 1024,  flag);

    gemm_bf16<<<dim3(64, 24), 256, 0, stream>>>((const short*)xb, (const short*)wT,
                                                qkv, vt, bb, bb + 1024, bb + 2048,
                                                1024, 3072, flag, 0, 1, 1);
    attn<<<dim3(64, 8), 512, 0, stream>>>(qkv, vt, yb);
    gemm_bf16<<<dim3(64, 8), 256, 0, stream>>>((const short*)yb, (const short*)(wT + 3072 * 1024),
                                               d_out, nullptr, bb + 3072, bb + 3072, bb + 3072,
                                               1024, 1024, flag, 1, 0, 0);
}